// Round 13
// baseline (170.577 us; speedup 1.0000x reference)
//
#include <hip/hip_runtime.h>
#include <hip/hip_bf16.h>
#include <math.h>

// Problem constants (from reference)
#define N_ATOMS 1024
#define E_EDGES 8192
#define M_ENV   8192
#define B_SEG   64
#define IN_CH   512
#define H_CH    1024
#define H_HEADS 8
#define D_HEAD  128

typedef __attribute__((ext_vector_type(8))) short short8_t;
typedef __attribute__((ext_vector_type(4))) float f32x4;
typedef __attribute__((ext_vector_type(4))) unsigned short ushort4_t;

__device__ __forceinline__ unsigned short f2bf(float x) {
    union { float f; unsigned u; } c; c.f = x;
    unsigned r = c.u + 0x7FFF + ((c.u >> 16) & 1);   // round-to-nearest-even
    return (unsigned short)(r >> 16);
}
__device__ __forceinline__ float bf2f(unsigned short b) {
    union { unsigned u; float f; } c; c.u = ((unsigned)b) << 16;
    return c.f;
}

// lower_bound over sorted batch_index (values 0..63)
__device__ __forceinline__ int lb_seg(const int* __restrict__ bi, int val) {
    int lo = 0, hi = E_EDGES;
    while (lo < hi) {
        const int mid = (lo + hi) >> 1;
        if (bi[mid] < val) lo = mid + 1; else hi = mid;
    }
    return lo;
}

// ---------------------------------------------------------------------------
// Kernel T+P: abT[m][n] = bf16(attn_bias[n][m]) (tiled transpose), and the
// first 32 blocks also build pkenv[e] = {atom|em<<10|seg<<23, envelope[em]}.
// ---------------------------------------------------------------------------
__global__ __launch_bounds__(256) void transpose_bias_pack_k(
    const float* __restrict__ ab,
    const int* __restrict__ atom_index,
    const int* __restrict__ edge_map,
    const int* __restrict__ batch_index,
    const float* __restrict__ envelope,
    unsigned short* __restrict__ abT,
    int2* __restrict__ pkenv) {
    __shared__ float tile[64][65];
    const int t = threadIdx.x;
    const int gid = blockIdx.x + gridDim.x * blockIdx.y;
    if (gid < E_EDGES / 256) {
        const int e = gid * 256 + t;
        const int a = atom_index[e];
        const int em = edge_map[e];
        const int bg = batch_index[e];
        int2 o;
        o.x = a | (em << 10) | (bg << 23);
        o.y = __float_as_int(envelope[em]);
        pkenv[e] = o;
    }
    const int m0 = blockIdx.x * 64;
    const int n0 = blockIdx.y * 64;
    const int c4 = (t & 15) * 4;
    const int r  = t >> 4;
#pragma unroll
    for (int it = 0; it < 4; ++it) {
        const int row = r + it * 16;
        const float4 v = *(const float4*)(ab + (size_t)(n0 + row) * M_ENV + m0 + c4);
        tile[row][c4 + 0] = v.x;
        tile[row][c4 + 1] = v.y;
        tile[row][c4 + 2] = v.z;
        tile[row][c4 + 3] = v.w;
    }
    __syncthreads();
    const int mr = t >> 2;
    const int nq = t & 3;
#pragma unroll
    for (int i = 0; i < 4; ++i) {
        const int nl = nq * 4 + i * 16;
        ushort4_t o;
        o[0] = f2bf(tile[nl + 0][mr]);
        o[1] = f2bf(tile[nl + 1][mr]);
        o[2] = f2bf(tile[nl + 2][mr]);
        o[3] = f2bf(tile[nl + 3][mr]);
        *(ushort4_t*)(abT + (size_t)(m0 + mr) * N_ATOMS + n0 + nl) = o;
    }
}

// ---------------------------------------------------------------------------
// Kernel 1b: batched 3-way projection GEMM, f32 inputs cast inline to bf16.
// ---------------------------------------------------------------------------
struct Proj3 {
    const float* A[3];
    const float* B[3];
    const float* bia[3];
    unsigned short* C[3];
};

__global__ __launch_bounds__(256) void proj3_k(Proj3 P) {
    __shared__ unsigned short As[64 * 40];
    __shared__ unsigned short Bs[64 * 40];
    const int t = threadIdx.x;
    const int w = t >> 6, lane = t & 63, g = lane >> 4, lo = lane & 15;
    const int m0 = blockIdx.x * 64, n0 = blockIdx.y * 64;
    const int z = blockIdx.z;
    const int srow = t >> 2, sc8 = (t & 3) * 8;
    const float scale = (z == 0) ? 0.08838834764831845f : 1.0f;   // q pre-scaled 1/sqrt(D)

    f32x4 acc[4];
#pragma unroll
    for (int nf = 0; nf < 4; ++nf) acc[nf] = (f32x4){0.f, 0.f, 0.f, 0.f};

    const float* gA = P.A[z] + (size_t)(m0 + srow) * IN_CH + sc8;
    const float* gB = P.B[z] + (size_t)(n0 + srow) * IN_CH + sc8;
    const int swr = srow * 40 + sc8;

    for (int k0 = 0; k0 < IN_CH; k0 += 32) {
        const float4 a0 = *(const float4*)(gA + k0);
        const float4 a1 = *(const float4*)(gA + k0 + 4);
        const float4 b0 = *(const float4*)(gB + k0);
        const float4 b1 = *(const float4*)(gB + k0 + 4);
        short8_t av, bvv;
        av[0]=f2bf(a0.x); av[1]=f2bf(a0.y); av[2]=f2bf(a0.z); av[3]=f2bf(a0.w);
        av[4]=f2bf(a1.x); av[5]=f2bf(a1.y); av[6]=f2bf(a1.z); av[7]=f2bf(a1.w);
        bvv[0]=f2bf(b0.x); bvv[1]=f2bf(b0.y); bvv[2]=f2bf(b0.z); bvv[3]=f2bf(b0.w);
        bvv[4]=f2bf(b1.x); bvv[5]=f2bf(b1.y); bvv[6]=f2bf(b1.z); bvv[7]=f2bf(b1.w);
        __syncthreads();
        *(short8_t*)&As[swr] = av;
        *(short8_t*)&Bs[swr] = bvv;
        __syncthreads();
        const short8_t af = *(const short8_t*)&As[(w * 16 + lo) * 40 + g * 8];
#pragma unroll
        for (int nf = 0; nf < 4; ++nf) {
            const short8_t bf = *(const short8_t*)&Bs[(nf * 16 + lo) * 40 + g * 8];
            acc[nf] = __builtin_amdgcn_mfma_f32_16x16x32_bf16(af, bf, acc[nf], 0, 0, 0);
        }
    }

#pragma unroll
    for (int nf = 0; nf < 4; ++nf) {
        const int col = n0 + nf * 16 + lo;
        const float bvv = P.bia[z][col];
#pragma unroll
        for (int r = 0; r < 4; ++r) {
            const int row = m0 + w * 16 + 4 * g + r;
            P.C[z][(size_t)row * H_CH + col] = f2bf((acc[nf][r] + bvv) * scale);
        }
    }
}

// ---------------------------------------------------------------------------
// Kernel S: SpT[h][a][n] = bf16( sum_d kb[a][h*128+d] * qb[n][h*128+d] )
// ---------------------------------------------------------------------------
__global__ __launch_bounds__(256) void spre_k(const unsigned short* __restrict__ kb,
                                              const unsigned short* __restrict__ qb,
                                              unsigned short* __restrict__ SpT) {
    __shared__ unsigned short As[64 * 40];
    __shared__ unsigned short Bs[64 * 40];
    const int t = threadIdx.x;
    const int w = t >> 6, lane = t & 63, g = lane >> 4, lo = lane & 15;
    const int a0 = blockIdx.x * 64, n0 = blockIdx.y * 64;
    const int h = blockIdx.z;
    const int srow = t >> 2, sc8 = (t & 3) * 8;

    f32x4 acc[4];
#pragma unroll
    for (int nf = 0; nf < 4; ++nf) acc[nf] = (f32x4){0.f, 0.f, 0.f, 0.f};

    const unsigned short* gA = kb + (size_t)(a0 + srow) * H_CH + h * D_HEAD + sc8;
    const unsigned short* gB = qb + (size_t)(n0 + srow) * H_CH + h * D_HEAD + sc8;
    const int swr = srow * 40 + sc8;

#pragma unroll
    for (int k0 = 0; k0 < D_HEAD; k0 += 32) {
        const short8_t av = *(const short8_t*)(gA + k0);
        const short8_t bv = *(const short8_t*)(gB + k0);
        __syncthreads();
        *(short8_t*)&As[swr] = av;
        *(short8_t*)&Bs[swr] = bv;
        __syncthreads();
        const short8_t af = *(const short8_t*)&As[(w * 16 + lo) * 40 + g * 8];
#pragma unroll
        for (int nf = 0; nf < 4; ++nf) {
            const short8_t bf = *(const short8_t*)&Bs[(nf * 16 + lo) * 40 + g * 8];
            acc[nf] = __builtin_amdgcn_mfma_f32_16x16x32_bf16(af, bf, acc[nf], 0, 0, 0);
        }
    }

    unsigned short* dst = SpT + ((size_t)h << 20);
#pragma unroll
    for (int nf = 0; nf < 4; ++nf) {
        const int col = n0 + nf * 16 + lo;
#pragma unroll
        for (int r = 0; r < 4; ++r) {
            const int row = a0 + w * 16 + 4 * g + r;
            dst[(size_t)row * N_ATOMS + col] = f2bf(acc[nf][r]);
        }
    }
}

// ---------------------------------------------------------------------------
// Kernel L4: parallel l-sum, XCD-partitioned by head (h = blockIdx.x & 7 so
// all blocks of head h land on XCD h; SpT[h] = 2MB stays L2-resident).
// 1-D grid 4096 = 64 segs x 8 n-tiles x 8 heads. Segment bounds via binary
// search in sorted batch_index (seg_offsets kernel deleted).
// ---------------------------------------------------------------------------
__global__ __launch_bounds__(256) void lsum4_k(const unsigned short* __restrict__ SpT,
                                               const unsigned short* __restrict__ abT,
                                               const int2* __restrict__ pkenv,
                                               const int* __restrict__ batch_index,
                                               unsigned short* __restrict__ rrbf) {
    __shared__ float lred[16][128];
    const int t = threadIdx.x;
    const int cslot = (t & 15) * 8;     // 8-col slice within 128
    const int eway = t >> 4;            // 16 edge ways
    const int id = blockIdx.x;
    const int h = id & 7;
    const int n0 = ((id >> 3) & 7) * 128;
    const int s = id >> 6;
    const unsigned short* Sh = SpT + ((size_t)h << 20);

    const int e0 = lb_seg(batch_index, s);
    const int e1 = lb_seg(batch_index, s + 1);
    float l[8] = {};

#pragma unroll 2
    for (int e = e0 + eway; e < e1; e += 16) {
        const int2 pk = pkenv[e];
        const float env = __int_as_float(pk.y);
        const int a_  = pk.x & 1023;
        const int em_ = (pk.x >> 10) & 8191;
        const short8_t su = *(const short8_t*)(Sh  + (size_t)a_  * N_ATOMS + n0 + cslot);
        const short8_t bu = *(const short8_t*)(abT + (size_t)em_ * N_ATOMS + n0 + cslot);
#pragma unroll
        for (int j = 0; j < 8; ++j)
            l[j] += __expf(bf2f((unsigned short)su[j]) + bf2f((unsigned short)bu[j])) * env;
    }
#pragma unroll
    for (int j = 0; j < 8; ++j) lred[eway][cslot + j] = l[j];
    __syncthreads();
    if (t < 128) {
        float sum = 0.f;
#pragma unroll
        for (int wv = 0; wv < 16; ++wv) sum += lred[wv][t];
        rrbf[(((size_t)h * B_SEG + s) << 10) + n0 + t] = f2bf(1.0f / (sum + 1e-16f));
    }
}

// ---------------------------------------------------------------------------
// Kernel PV7b: pv7 (77us proven) + XCD-partitioned 1-D grid: h = id & 7 so
// each head's blocks share one XCD and SpT[h] (2MB) stays in that XCD's L2.
// Grid 1024 = 8 kc x 16 n-tiles x 8 heads; 256 thr = 4 waves; 4 blocks/CU.
// ---------------------------------------------------------------------------
#define PLDS_STRIDE 76

#define LGKM_BARRIER()                                          \
    do {                                                        \
        asm volatile("s_waitcnt lgkmcnt(0)" ::: "memory");      \
        __builtin_amdgcn_sched_barrier(0);                      \
        __builtin_amdgcn_s_barrier();                           \
    } while (0)

#define PV_GATHER(cc)                                                            \
    do {                                                                         \
        const int eb_ = ebase + (cc) * 64;                                       \
        _Pragma("unroll")                                                        \
        for (int ei = 0; ei < 2; ++ei) {                                         \
            const int e = eb_ + ei * 32 + (lane >> 1);                           \
            const int2 pk = pkenv[e];                                            \
            pkP[ei] = pk.x;                                                      \
            enP[ei] = __int_as_float(pk.y);                                      \
            const int a_  = pk.x & 1023;                                         \
            const int em_ = (pk.x >> 10) & 8191;                                 \
            sP[ei] = *(const short8_t*)(Sh  + (size_t)a_  * N_ATOMS + ncol8);    \
            bP[ei] = *(const short8_t*)(abT + (size_t)em_ * N_ATOMS + ncol8);    \
        }                                                                        \
        {                                                                        \
            /* V atoms via shuffle: edge x held by lane 2*(x&31), set x>>5 */    \
            const int sl0 = (el & 31) * 2;                                       \
            const int va00 = __shfl(pkP[0], sl0);                                \
            const int va01 = __shfl(pkP[1], sl0);                                \
            const int va10 = __shfl(pkP[0], sl0 + 2);                            \
            const int va11 = __shfl(pkP[1], sl0 + 2);                            \
            const int aA = ((el < 32) ? va00 : va01) & 1023;                     \
            const int aB = ((el < 32) ? va10 : va11) & 1023;                     \
            const unsigned short* pA = vh + (size_t)aA * H_CH;                   \
            const unsigned short* pB = vh + (size_t)aB * H_CH;                   \
            vP[0] = *(const short8_t*)(pA);                                      \
            vP[1] = *(const short8_t*)(pA + 8);                                  \
            vP[2] = *(const short8_t*)(pB);                                      \
            vP[3] = *(const short8_t*)(pB + 8);                                  \
        }                                                                        \
    } while (0)

__global__ __launch_bounds__(256, 4) void pv7b_k(
    const unsigned short* __restrict__ SpT,   // [H][1024][1024] bf16
    const unsigned short* __restrict__ vb,    // [N][H_CH] bf16
    const unsigned short* __restrict__ abT,   // [M][N] bf16
    const int2* __restrict__ pkenv,           // [E] {idx, env}
    const unsigned short* __restrict__ rrbf,  // [H][B_SEG][N] bf16
    unsigned short* __restrict__ part)        // [8][N][H_CH] bf16
{
    __shared__ unsigned short plds[64][PLDS_STRIDE]; // P~ rows n-local, cols e-local
    __shared__ unsigned short vst[128][72];          // V^T swizzled
    __shared__ unsigned short rrlds[64 * 64];        // rr[s][col] XOR-swizzled

    const int t = threadIdx.x;
    const int wid = t >> 6, lane = t & 63;
    const int g = lane >> 4, lo = lane & 15;
    const int half = lane & 1;
    const int id = blockIdx.x;
    const int h  = id & 7;                    // XCD partition key
    const int n0 = ((id >> 3) & 15) * 64;
    const int kc = id >> 7;
    const int ebase = kc * 1024;
    const int c8l = wid * 16 + half * 8;           // block-local col base (8 cols)
    const int ncol8 = n0 + c8l;
    const unsigned short* Sh = SpT + ((size_t)h << 20);
    const int el = (lane & 31) * 2;           // V: edge pair within sub-chunk
    const int dh = (t >> 5) * 16;             // V: 16-d slice
    const unsigned short* vh = vb + h * D_HEAD + dh;

    // ---- stage rr slab: all 64 segments x block's 64 cols (bf16, swizzled) ----
    {
        const int s_ = t >> 2;
        const int c16 = (t & 3) * 16;
        const unsigned short* src = rrbf + (((size_t)h * B_SEG + s_) << 10) + n0 + c16;
#pragma unroll
        for (int b2 = 0; b2 < 2; ++b2) {
            const int cb = (t & 3) * 2 + b2;
            const int pos = cb ^ (s_ & 7);
            *(short8_t*)&rrlds[s_ * 64 + pos * 8] = *(const short8_t*)(src + b2 * 8);
        }
    }
    __syncthreads();

    f32x4 osg[8];
#pragma unroll
    for (int di = 0; di < 8; ++di) osg[di] = (f32x4){0.f, 0.f, 0.f, 0.f};

    int pkP[2];
    short8_t sP[2], bP[2];
    float enP[2];
    short8_t vP[4];

    PV_GATHER(0);

    for (int sc = 0; sc < 16; ++sc) {
        LGKM_BARRIER();    // barA: previous MFMA's LDS reads are done (lgkm only)

        // ---- V^T pack (swizzled; conflict-free u32 writes) ----
#pragma unroll
        for (int j = 0; j < 8; ++j) {
            const int d0 = dh + j;
            const int c0 = ((((el >> 3) ^ (d0 >> 4)) & 7) << 3) + (el & 7);
            *(unsigned*)&vst[d0][c0] =
                (unsigned)(unsigned short)vP[0][j] |
                ((unsigned)(unsigned short)vP[2][j] << 16);
            const int d1 = dh + 8 + j;
            const int c1 = ((((el >> 3) ^ (d1 >> 4)) & 7) << 3) + (el & 7);
            *(unsigned*)&vst[d1][c1] =
                (unsigned)(unsigned short)vP[1][j] |
                ((unsigned)(unsigned short)vP[3][j] << 16);
        }
        // ---- P~ = exp(S+bias)*env^2*rr -> plds (rows = 8 cols, col = edge) ----
#pragma unroll
        for (int ei = 0; ei < 2; ++ei) {
            const int bseg = (pkP[ei] >> 23) & 63;
            const int cbr = (wid * 2 + half) ^ (bseg & 7);
            const short8_t rr8 = *(const short8_t*)&rrlds[bseg * 64 + cbr * 8];
            const float ee2 = enP[ei] * enP[ei];
            const int e_loc = ei * 32 + (lane >> 1);
#pragma unroll
            for (int j = 0; j < 8; ++j) {
                const float sv = bf2f((unsigned short)sP[ei][j]) + bf2f((unsigned short)bP[ei][j]);
                const float w_ = __expf(sv) * ee2 * bf2f((unsigned short)rr8[j]);
                plds[c8l + j][e_loc] = f2bf(w_);
            }
        }
        LGKM_BARRIER();    // barB: LDS published

        // issue next sub-chunk's gathers now; latency hides under MFMA
        if (sc + 1 < 16) PV_GATHER(sc + 1);

        const short8_t af0 = *(const short8_t*)&plds[wid * 16 + lo][g * 8];
        const short8_t af1 = *(const short8_t*)&plds[wid * 16 + lo][32 + g * 8];
        __builtin_amdgcn_s_setprio(1);
#pragma unroll
        for (int di = 0; di < 8; ++di) {
            const short8_t b0 = *(const short8_t*)&vst[di * 16 + lo][((g ^ di) & 7) << 3];
            osg[di] = __builtin_amdgcn_mfma_f32_16x16x32_bf16(af0, b0, osg[di], 0, 0, 0);
            const short8_t b1 = *(const short8_t*)&vst[di * 16 + lo][(((4 + g) ^ di) & 7) << 3];
            osg[di] = __builtin_amdgcn_mfma_f32_16x16x32_bf16(af1, b1, osg[di], 0, 0, 0);
        }
        __builtin_amdgcn_s_setprio(0);
    }

    // store bf16 partial: rows n0+wid*16+4g+r, cols h*128 + di*16 + lo
#pragma unroll
    for (int di = 0; di < 8; ++di)
#pragma unroll
        for (int r = 0; r < 4; ++r)
            part[((size_t)kc * N_ATOMS + n0 + wid * 16 + 4 * g + r) * H_CH
                 + h * D_HEAD + di * 16 + lo] = f2bf(osg[di][r]);
}

// ---------------------------------------------------------------------------
// Kernel 3: LayerNorm of sum of 8 bf16 partials (biased var, eps 1e-7), bf16 out
// ---------------------------------------------------------------------------
__global__ __launch_bounds__(256) void layernorm8_k(const unsigned short* __restrict__ part,
                                                    const float* __restrict__ gm,
                                                    const float* __restrict__ bt,
                                                    unsigned short* __restrict__ y) {
    const int row = blockIdx.x;
    const int t = threadIdx.x;
    const size_t base = (size_t)row * H_CH;
    float4 v = make_float4(0.f, 0.f, 0.f, 0.f);
#pragma unroll
    for (int p = 0; p < 8; ++p) {
        const ushort4_t a = ((const ushort4_t*)(part + (size_t)p * N_ATOMS * H_CH + base))[t];
        v.x += bf2f(a[0]); v.y += bf2f(a[1]); v.z += bf2f(a[2]); v.w += bf2f(a[3]);
    }

    float s  = v.x + v.y + v.z + v.w;
    float s2 = v.x * v.x + v.y * v.y + v.z * v.z + v.w * v.w;
#pragma unroll
    for (int o = 1; o < 64; o <<= 1) {
        s  += __shfl_xor(s, o);
        s2 += __shfl_xor(s2, o);
    }
    __shared__ float red[8];
    const int wid = t >> 6;
    if ((t & 63) == 0) { red[wid] = s; red[wid + 4] = s2; }
    __syncthreads();
    const float ts  = red[0] + red[1] + red[2] + red[3];
    const float ts2 = red[4] + red[5] + red[6] + red[7];

    const float mean = ts * (1.0f / (float)H_CH);
    const float var  = ts2 * (1.0f / (float)H_CH) - mean * mean;
    const float rstd = rsqrtf(var + 1e-7f);

    const float4 gv = ((const float4*)gm)[t];
    const float4 bv = ((const float4*)bt)[t];
    ushort4_t o;
    o[0] = f2bf((v.x - mean) * rstd * gv.x + bv.x);
    o[1] = f2bf((v.y - mean) * rstd * gv.y + bv.y);
    o[2] = f2bf((v.z - mean) * rstd * gv.z + bv.z);
    o[3] = f2bf((v.w - mean) * rstd * gv.w + bv.w);
    ((ushort4_t*)(y + base))[t] = o;
}

// ---------------------------------------------------------------------------
// Kernel 4: final GEMM  out[1024,512] = ln_o(bf16) @ Wo(f32, cast inline)^T + bo
// ---------------------------------------------------------------------------
__global__ __launch_bounds__(256) void gemm_out_k(const unsigned short* __restrict__ A,
                                                  const float* __restrict__ B,
                                                  const float* __restrict__ bias,
                                                  float* __restrict__ C) {
    __shared__ unsigned short As[64 * 40];
    __shared__ unsigned short Bs[64 * 40];
    const int t = threadIdx.x;
    const int w = t >> 6, lane = t & 63, g = lane >> 4, lo = lane & 15;
    const int m0 = blockIdx.x * 64, n0 = blockIdx.y * 64;
    const int srow = t >> 2, sc8 = (t & 3) * 8;

    f32x4 acc[4];
#pragma unroll
    for (int nf = 0; nf < 4; ++nf) acc[nf] = (f32x4){0.f, 0.f, 0.f, 0.f};

    const unsigned short* gA = A + (size_t)(m0 + srow) * H_CH + sc8;
    const float* gB = B + (size_t)(n0 + srow) * H_CH + sc8;
    const int swr = srow * 40 + sc8;

    for (int k0 = 0; k0 < H_CH; k0 += 32) {
        const short8_t av = *(const short8_t*)(gA + k0);
        const float4 b0 = *(const float4*)(gB + k0);
        const float4 b1 = *(const float4*)(gB + k0 + 4);
        short8_t bvv;
        bvv[0]=f2bf(b0.x); bvv[1]=f2bf(b0.y); bvv[2]=f2bf(b0.z); bvv[3]=f2bf(b0.w);
        bvv[4]=f2bf(b1.x); bvv[5]=f2bf(b1.y); bvv[6]=f2bf(b1.z); bvv[7]=f2bf(b1.w);
        __syncthreads();
        *(short8_t*)&As[swr] = av;
        *(short8_t*)&Bs[swr] = bvv;
        __syncthreads();
        const short8_t af = *(const short8_t*)&As[(w * 16 + lo) * 40 + g * 8];
#pragma unroll
        for (int nf = 0; nf < 4; ++nf) {
            const short8_t bf = *(const short8_t*)&Bs[(nf * 16 + lo) * 40 + g * 8];
            acc[nf] = __builtin_amdgcn_mfma_f32_16x16x32_bf16(af, bf, acc[nf], 0, 0, 0);
        }
    }

#pragma unroll
    for (int nf = 0; nf < 4; ++nf) {
        const int col = n0 + nf * 16 + lo;
        const float bvv = bias[col];
#pragma unroll
        for (int r = 0; r < 4; ++r) {
            const int row = m0 + w * 16 + 4 * g + r;
            C[(size_t)row * IN_CH + col] = acc[nf][r] + bvv;
        }
    }
}

// ---------------------------------------------------------------------------
// Launch
// ---------------------------------------------------------------------------
extern "C" void kernel_launch(void* const* d_in, const int* in_sizes, int n_in,
                              void* d_out, int out_size, void* d_ws, size_t ws_size,
                              hipStream_t stream) {
    (void)in_sizes; (void)n_in; (void)out_size; (void)ws_size;
    const float* q         = (const float*)d_in[0];
    const float* k         = (const float*)d_in[1];
    const float* v         = (const float*)d_in[2];
    const float* envelope  = (const float*)d_in[3];
    const float* attn_bias = (const float*)d_in[4];
    const float* Wq        = (const float*)d_in[5];
    const float* bq        = (const float*)d_in[6];
    const float* Wk        = (const float*)d_in[7];
    const float* bk        = (const float*)d_in[8];
    const float* Wv        = (const float*)d_in[9];
    const float* bv        = (const float*)d_in[10];
    const float* ln_g      = (const float*)d_in[11];
    const float* ln_b      = (const float*)d_in[12];
    const float* Wo        = (const float*)d_in[13];
    const float* bo        = (const float*)d_in[14];
    const int* atom_index  = (const int*)d_in[15];
    const int* batch_index = (const int*)d_in[16];
    const int* edge_map    = (const int*)d_in[17];
    float* out = (float*)d_out;

    char* w8 = (char*)d_ws;
    unsigned short* SpT   = (unsigned short*)(w8);                      // 0..16M
    unsigned short* abT   = (unsigned short*)(w8 + (16u << 20));        // 16..32M
    unsigned short* partb = (unsigned short*)(w8 + (32u << 20));        // 32..48M
    unsigned short* vbuf  = (unsigned short*)(w8 + (48u << 20));        // 48..50M
    unsigned short* qb    = (unsigned short*)(w8 + (50u << 20));        // 50..52M
    unsigned short* kb    = (unsigned short*)(w8 + (52u << 20));        // 52..54M
    unsigned short* ln_o  = (unsigned short*)(w8 + (54u << 20));        // 54..56M
    unsigned short* rrbf  = (unsigned short*)(w8 + (56u << 20));        // 1 MB bf16 [H][64][1024]
    int2*           pkenv = (int2*)          (w8 + (58u << 20));        // 64 KB

    transpose_bias_pack_k<<<dim3(M_ENV / 64, N_ATOMS / 64), 256, 0, stream>>>(
        attn_bias, atom_index, edge_map, batch_index, envelope, abT, pkenv);

    Proj3 pj;
    pj.A[0] = q;   pj.A[1] = k;   pj.A[2] = v;
    pj.B[0] = Wq;  pj.B[1] = Wk;  pj.B[2] = Wv;
    pj.bia[0] = bq; pj.bia[1] = bk; pj.bia[2] = bv;
    pj.C[0] = qb;  pj.C[1] = kb;  pj.C[2] = vbuf;
    proj3_k<<<dim3(16, 16, 3), 256, 0, stream>>>(pj);

    spre_k<<<dim3(16, 16, H_HEADS), 256, 0, stream>>>(kb, qb, SpT);

    lsum4_k<<<B_SEG * 8 * H_HEADS, 256, 0, stream>>>(SpT, abT, pkenv, batch_index, rrbf);

    pv7b_k<<<8 * 16 * H_HEADS, 256, 0, stream>>>(SpT, vbuf, abT, pkenv, rrbf, partb);

    layernorm8_k<<<N_ATOMS, 256, 0, stream>>>(partb, ln_g, ln_b, ln_o);

    gemm_out_k<<<dim3(16, 8), 256, 0, stream>>>(ln_o, Wo, bo, out);
}

// Round 14
// 159.767 us; speedup vs baseline: 1.0677x; 1.0677x over previous
//
#include <hip/hip_runtime.h>
#include <hip/hip_bf16.h>
#include <math.h>

// Problem constants (from reference)
#define N_ATOMS 1024
#define E_EDGES 8192
#define M_ENV   8192
#define B_SEG   64
#define IN_CH   512
#define H_CH    1024
#define H_HEADS 8
#define D_HEAD  128

typedef __attribute__((ext_vector_type(8))) short short8_t;
typedef __attribute__((ext_vector_type(4))) float f32x4;
typedef __attribute__((ext_vector_type(4))) unsigned short ushort4_t;

__device__ __forceinline__ unsigned short f2bf(float x) {
    union { float f; unsigned u; } c; c.f = x;
    unsigned r = c.u + 0x7FFF + ((c.u >> 16) & 1);   // round-to-nearest-even
    return (unsigned short)(r >> 16);
}
__device__ __forceinline__ float bf2f(unsigned short b) {
    union { unsigned u; float f; } c; c.u = ((unsigned)b) << 16;
    return c.f;
}

// lower_bound over sorted batch_index (values 0..63)
__device__ __forceinline__ int lb_seg(const int* __restrict__ bi, int val) {
    int lo = 0, hi = E_EDGES;
    while (lo < hi) {
        const int mid = (lo + hi) >> 1;
        if (bi[mid] < val) lo = mid + 1; else hi = mid;
    }
    return lo;
}

// ---------------------------------------------------------------------------
// Kernel T+P: abT[m][n] = bf16(attn_bias[n][m]) (tiled transpose); the first
// 32 blocks also build pkenv[e] = {atom|em<<10|seg<<23, envelope[em]}.
// ---------------------------------------------------------------------------
__global__ __launch_bounds__(256) void transpose_bias_pack_k(
    const float* __restrict__ ab,
    const int* __restrict__ atom_index,
    const int* __restrict__ edge_map,
    const int* __restrict__ batch_index,
    const float* __restrict__ envelope,
    unsigned short* __restrict__ abT,
    int2* __restrict__ pkenv) {
    __shared__ float tile[64][65];
    const int t = threadIdx.x;
    const int gid = blockIdx.x + gridDim.x * blockIdx.y;
    if (gid < E_EDGES / 256) {
        const int e = gid * 256 + t;
        const int a = atom_index[e];
        const int em = edge_map[e];
        const int bg = batch_index[e];
        int2 o;
        o.x = a | (em << 10) | (bg << 23);
        o.y = __float_as_int(envelope[em]);
        pkenv[e] = o;
    }
    const int m0 = blockIdx.x * 64;
    const int n0 = blockIdx.y * 64;
    const int c4 = (t & 15) * 4;
    const int r  = t >> 4;
#pragma unroll
    for (int it = 0; it < 4; ++it) {
        const int row = r + it * 16;
        const float4 v = *(const float4*)(ab + (size_t)(n0 + row) * M_ENV + m0 + c4);
        tile[row][c4 + 0] = v.x;
        tile[row][c4 + 1] = v.y;
        tile[row][c4 + 2] = v.z;
        tile[row][c4 + 3] = v.w;
    }
    __syncthreads();
    const int mr = t >> 2;
    const int nq = t & 3;
#pragma unroll
    for (int i = 0; i < 4; ++i) {
        const int nl = nq * 4 + i * 16;
        ushort4_t o;
        o[0] = f2bf(tile[nl + 0][mr]);
        o[1] = f2bf(tile[nl + 1][mr]);
        o[2] = f2bf(tile[nl + 2][mr]);
        o[3] = f2bf(tile[nl + 3][mr]);
        *(ushort4_t*)(abT + (size_t)(m0 + mr) * N_ATOMS + n0 + nl) = o;
    }
}

// ---------------------------------------------------------------------------
// Kernel 1b: batched 3-way projection GEMM, f32 inputs cast inline to bf16.
// ---------------------------------------------------------------------------
struct Proj3 {
    const float* A[3];
    const float* B[3];
    const float* bia[3];
    unsigned short* C[3];
};

__global__ __launch_bounds__(256) void proj3_k(Proj3 P) {
    __shared__ unsigned short As[64 * 40];
    __shared__ unsigned short Bs[64 * 40];
    const int t = threadIdx.x;
    const int w = t >> 6, lane = t & 63, g = lane >> 4, lo = lane & 15;
    const int m0 = blockIdx.x * 64, n0 = blockIdx.y * 64;
    const int z = blockIdx.z;
    const int srow = t >> 2, sc8 = (t & 3) * 8;
    const float scale = (z == 0) ? 0.08838834764831845f : 1.0f;   // q pre-scaled 1/sqrt(D)

    f32x4 acc[4];
#pragma unroll
    for (int nf = 0; nf < 4; ++nf) acc[nf] = (f32x4){0.f, 0.f, 0.f, 0.f};

    const float* gA = P.A[z] + (size_t)(m0 + srow) * IN_CH + sc8;
    const float* gB = P.B[z] + (size_t)(n0 + srow) * IN_CH + sc8;
    const int swr = srow * 40 + sc8;

    for (int k0 = 0; k0 < IN_CH; k0 += 32) {
        const float4 a0 = *(const float4*)(gA + k0);
        const float4 a1 = *(const float4*)(gA + k0 + 4);
        const float4 b0 = *(const float4*)(gB + k0);
        const float4 b1 = *(const float4*)(gB + k0 + 4);
        short8_t av, bvv;
        av[0]=f2bf(a0.x); av[1]=f2bf(a0.y); av[2]=f2bf(a0.z); av[3]=f2bf(a0.w);
        av[4]=f2bf(a1.x); av[5]=f2bf(a1.y); av[6]=f2bf(a1.z); av[7]=f2bf(a1.w);
        bvv[0]=f2bf(b0.x); bvv[1]=f2bf(b0.y); bvv[2]=f2bf(b0.z); bvv[3]=f2bf(b0.w);
        bvv[4]=f2bf(b1.x); bvv[5]=f2bf(b1.y); bvv[6]=f2bf(b1.z); bvv[7]=f2bf(b1.w);
        __syncthreads();
        *(short8_t*)&As[swr] = av;
        *(short8_t*)&Bs[swr] = bvv;
        __syncthreads();
        const short8_t af = *(const short8_t*)&As[(w * 16 + lo) * 40 + g * 8];
#pragma unroll
        for (int nf = 0; nf < 4; ++nf) {
            const short8_t bf = *(const short8_t*)&Bs[(nf * 16 + lo) * 40 + g * 8];
            acc[nf] = __builtin_amdgcn_mfma_f32_16x16x32_bf16(af, bf, acc[nf], 0, 0, 0);
        }
    }

#pragma unroll
    for (int nf = 0; nf < 4; ++nf) {
        const int col = n0 + nf * 16 + lo;
        const float bvv = P.bia[z][col];
#pragma unroll
        for (int r = 0; r < 4; ++r) {
            const int row = m0 + w * 16 + 4 * g + r;
            P.C[z][(size_t)row * H_CH + col] = f2bf((acc[nf][r] + bvv) * scale);
        }
    }
}

// ---------------------------------------------------------------------------
// Kernel S: SpT[h][a][n] = bf16( sum_d kb[a][h*128+d] * qb[n][h*128+d] )
// ---------------------------------------------------------------------------
__global__ __launch_bounds__(256) void spre_k(const unsigned short* __restrict__ kb,
                                              const unsigned short* __restrict__ qb,
                                              unsigned short* __restrict__ SpT) {
    __shared__ unsigned short As[64 * 40];
    __shared__ unsigned short Bs[64 * 40];
    const int t = threadIdx.x;
    const int w = t >> 6, lane = t & 63, g = lane >> 4, lo = lane & 15;
    const int a0 = blockIdx.x * 64, n0 = blockIdx.y * 64;
    const int h = blockIdx.z;
    const int srow = t >> 2, sc8 = (t & 3) * 8;

    f32x4 acc[4];
#pragma unroll
    for (int nf = 0; nf < 4; ++nf) acc[nf] = (f32x4){0.f, 0.f, 0.f, 0.f};

    const unsigned short* gA = kb + (size_t)(a0 + srow) * H_CH + h * D_HEAD + sc8;
    const unsigned short* gB = qb + (size_t)(n0 + srow) * H_CH + h * D_HEAD + sc8;
    const int swr = srow * 40 + sc8;

#pragma unroll
    for (int k0 = 0; k0 < D_HEAD; k0 += 32) {
        const short8_t av = *(const short8_t*)(gA + k0);
        const short8_t bv = *(const short8_t*)(gB + k0);
        __syncthreads();
        *(short8_t*)&As[swr] = av;
        *(short8_t*)&Bs[swr] = bv;
        __syncthreads();
        const short8_t af = *(const short8_t*)&As[(w * 16 + lo) * 40 + g * 8];
#pragma unroll
        for (int nf = 0; nf < 4; ++nf) {
            const short8_t bf = *(const short8_t*)&Bs[(nf * 16 + lo) * 40 + g * 8];
            acc[nf] = __builtin_amdgcn_mfma_f32_16x16x32_bf16(af, bf, acc[nf], 0, 0, 0);
        }
    }

    unsigned short* dst = SpT + ((size_t)h << 20);
#pragma unroll
    for (int nf = 0; nf < 4; ++nf) {
        const int col = n0 + nf * 16 + lo;
#pragma unroll
        for (int r = 0; r < 4; ++r) {
            const int row = a0 + w * 16 + 4 * g + r;
            dst[(size_t)row * N_ATOMS + col] = f2bf(acc[nf][r]);
        }
    }
}

// ---------------------------------------------------------------------------
// Kernel L5: parallel l-sum, R12-proven 3-D grid (8 n-tiles, 8 heads, 64 segs),
// segment bounds via binary search (no seg_offsets kernel).
// rrbf[h][s][n] = bf16(1/(l+1e-16)).
// ---------------------------------------------------------------------------
__global__ __launch_bounds__(256) void lsum5_k(const unsigned short* __restrict__ SpT,
                                               const unsigned short* __restrict__ abT,
                                               const int2* __restrict__ pkenv,
                                               const int* __restrict__ batch_index,
                                               unsigned short* __restrict__ rrbf) {
    __shared__ float lred[16][128];
    const int t = threadIdx.x;
    const int cslot = (t & 15) * 8;     // 8-col slice within 128
    const int eway = t >> 4;            // 16 edge ways
    const int n0 = blockIdx.x * 128;
    const int h = blockIdx.y, s = blockIdx.z;
    const unsigned short* Sh = SpT + ((size_t)h << 20);

    const int e0 = lb_seg(batch_index, s);
    const int e1 = lb_seg(batch_index, s + 1);
    float l[8] = {};

#pragma unroll 2
    for (int e = e0 + eway; e < e1; e += 16) {
        const int2 pk = pkenv[e];
        const float env = __int_as_float(pk.y);
        const int a_  = pk.x & 1023;
        const int em_ = (pk.x >> 10) & 8191;
        const short8_t su = *(const short8_t*)(Sh  + (size_t)a_  * N_ATOMS + n0 + cslot);
        const short8_t bu = *(const short8_t*)(abT + (size_t)em_ * N_ATOMS + n0 + cslot);
#pragma unroll
        for (int j = 0; j < 8; ++j)
            l[j] += __expf(bf2f((unsigned short)su[j]) + bf2f((unsigned short)bu[j])) * env;
    }
#pragma unroll
    for (int j = 0; j < 8; ++j) lred[eway][cslot + j] = l[j];
    __syncthreads();
    if (t < 128) {
        float sum = 0.f;
#pragma unroll
        for (int wv = 0; wv < 16; ++wv) sum += lred[wv][t];
        rrbf[(((size_t)h * B_SEG + s) << 10) + n0 + t] = f2bf(1.0f / (sum + 1e-16f));
    }
}

// ---------------------------------------------------------------------------
// Kernel PV7 (R12, 77us proven): dense gather-GEMM, address-minimized.
//  - S/bias 16B/lane; V atoms via __shfl from in-register pkenv
//  - plds stride 76 (bank-conflict pad); rr slab in LDS; lgkm-only barriers
//  - 1-deep prefetch; 4 blocks/CU; 3-D grid dim3(16, 8, 8) (proven dispatch)
// ---------------------------------------------------------------------------
#define PLDS_STRIDE 76

#define LGKM_BARRIER()                                          \
    do {                                                        \
        asm volatile("s_waitcnt lgkmcnt(0)" ::: "memory");      \
        __builtin_amdgcn_sched_barrier(0);                      \
        __builtin_amdgcn_s_barrier();                           \
    } while (0)

#define PV_GATHER(cc)                                                            \
    do {                                                                         \
        const int eb_ = ebase + (cc) * 64;                                       \
        _Pragma("unroll")                                                        \
        for (int ei = 0; ei < 2; ++ei) {                                         \
            const int e = eb_ + ei * 32 + (lane >> 1);                           \
            const int2 pk = pkenv[e];                                            \
            pkP[ei] = pk.x;                                                      \
            enP[ei] = __int_as_float(pk.y);                                      \
            const int a_  = pk.x & 1023;                                         \
            const int em_ = (pk.x >> 10) & 8191;                                 \
            sP[ei] = *(const short8_t*)(Sh  + (size_t)a_  * N_ATOMS + ncol8);    \
            bP[ei] = *(const short8_t*)(abT + (size_t)em_ * N_ATOMS + ncol8);    \
        }                                                                        \
        {                                                                        \
            /* V atoms via shuffle: edge x held by lane 2*(x&31), set x>>5 */    \
            const int sl0 = (el & 31) * 2;                                       \
            const int va00 = __shfl(pkP[0], sl0);                                \
            const int va01 = __shfl(pkP[1], sl0);                                \
            const int va10 = __shfl(pkP[0], sl0 + 2);                            \
            const int va11 = __shfl(pkP[1], sl0 + 2);                            \
            const int aA = ((el < 32) ? va00 : va01) & 1023;                     \
            const int aB = ((el < 32) ? va10 : va11) & 1023;                     \
            const unsigned short* pA = vh + (size_t)aA * H_CH;                   \
            const unsigned short* pB = vh + (size_t)aB * H_CH;                   \
            vP[0] = *(const short8_t*)(pA);                                      \
            vP[1] = *(const short8_t*)(pA + 8);                                  \
            vP[2] = *(const short8_t*)(pB);                                      \
            vP[3] = *(const short8_t*)(pB + 8);                                  \
        }                                                                        \
    } while (0)

__global__ __launch_bounds__(256, 4) void pv7_k(
    const unsigned short* __restrict__ SpT,   // [H][1024][1024] bf16
    const unsigned short* __restrict__ vb,    // [N][H_CH] bf16
    const unsigned short* __restrict__ abT,   // [M][N] bf16
    const int2* __restrict__ pkenv,           // [E] {idx, env}
    const unsigned short* __restrict__ rrbf,  // [H][B_SEG][N] bf16
    unsigned short* __restrict__ part)        // [8][N][H_CH] bf16
{
    __shared__ unsigned short plds[64][PLDS_STRIDE]; // P~ rows n-local, cols e-local
    __shared__ unsigned short vst[128][72];          // V^T swizzled
    __shared__ unsigned short rrlds[64 * 64];        // rr[s][col] XOR-swizzled

    const int t = threadIdx.x;
    const int wid = t >> 6, lane = t & 63;
    const int g = lane >> 4, lo = lane & 15;
    const int half = lane & 1;
    const int n0 = blockIdx.x * 64;
    const int h = blockIdx.y, kc = blockIdx.z;
    const int ebase = kc * 1024;
    const int c8l = wid * 16 + half * 8;           // block-local col base (8 cols)
    const int ncol8 = n0 + c8l;
    const unsigned short* Sh = SpT + ((size_t)h << 20);
    const int el = (lane & 31) * 2;           // V: edge pair within sub-chunk
    const int dh = (t >> 5) * 16;             // V: 16-d slice
    const unsigned short* vh = vb + h * D_HEAD + dh;

    // ---- stage rr slab: all 64 segments x block's 64 cols (bf16, swizzled) ----
    {
        const int s_ = t >> 2;
        const int c16 = (t & 3) * 16;
        const unsigned short* src = rrbf + (((size_t)h * B_SEG + s_) << 10) + n0 + c16;
#pragma unroll
        for (int b2 = 0; b2 < 2; ++b2) {
            const int cb = (t & 3) * 2 + b2;
            const int pos = cb ^ (s_ & 7);
            *(short8_t*)&rrlds[s_ * 64 + pos * 8] = *(const short8_t*)(src + b2 * 8);
        }
    }
    __syncthreads();

    f32x4 osg[8];
#pragma unroll
    for (int di = 0; di < 8; ++di) osg[di] = (f32x4){0.f, 0.f, 0.f, 0.f};

    int pkP[2];
    short8_t sP[2], bP[2];
    float enP[2];
    short8_t vP[4];

    PV_GATHER(0);

    for (int sc = 0; sc < 16; ++sc) {
        LGKM_BARRIER();    // barA: previous MFMA's LDS reads are done (lgkm only)

        // ---- V^T pack (swizzled; conflict-free u32 writes) ----
#pragma unroll
        for (int j = 0; j < 8; ++j) {
            const int d0 = dh + j;
            const int c0 = ((((el >> 3) ^ (d0 >> 4)) & 7) << 3) + (el & 7);
            *(unsigned*)&vst[d0][c0] =
                (unsigned)(unsigned short)vP[0][j] |
                ((unsigned)(unsigned short)vP[2][j] << 16);
            const int d1 = dh + 8 + j;
            const int c1 = ((((el >> 3) ^ (d1 >> 4)) & 7) << 3) + (el & 7);
            *(unsigned*)&vst[d1][c1] =
                (unsigned)(unsigned short)vP[1][j] |
                ((unsigned)(unsigned short)vP[3][j] << 16);
        }
        // ---- P~ = exp(S+bias)*env^2*rr -> plds (rows = 8 cols, col = edge) ----
#pragma unroll
        for (int ei = 0; ei < 2; ++ei) {
            const int bseg = (pkP[ei] >> 23) & 63;
            const int cbr = (wid * 2 + half) ^ (bseg & 7);
            const short8_t rr8 = *(const short8_t*)&rrlds[bseg * 64 + cbr * 8];
            const float ee2 = enP[ei] * enP[ei];
            const int e_loc = ei * 32 + (lane >> 1);
#pragma unroll
            for (int j = 0; j < 8; ++j) {
                const float sv = bf2f((unsigned short)sP[ei][j]) + bf2f((unsigned short)bP[ei][j]);
                const float w_ = __expf(sv) * ee2 * bf2f((unsigned short)rr8[j]);
                plds[c8l + j][e_loc] = f2bf(w_);
            }
        }
        LGKM_BARRIER();    // barB: LDS published

        // issue next sub-chunk's gathers now; latency hides under MFMA
        if (sc + 1 < 16) PV_GATHER(sc + 1);

        const short8_t af0 = *(const short8_t*)&plds[wid * 16 + lo][g * 8];
        const short8_t af1 = *(const short8_t*)&plds[wid * 16 + lo][32 + g * 8];
        __builtin_amdgcn_s_setprio(1);
#pragma unroll
        for (int di = 0; di < 8; ++di) {
            const short8_t b0 = *(const short8_t*)&vst[di * 16 + lo][((g ^ di) & 7) << 3];
            osg[di] = __builtin_amdgcn_mfma_f32_16x16x32_bf16(af0, b0, osg[di], 0, 0, 0);
            const short8_t b1 = *(const short8_t*)&vst[di * 16 + lo][(((4 + g) ^ di) & 7) << 3];
            osg[di] = __builtin_amdgcn_mfma_f32_16x16x32_bf16(af1, b1, osg[di], 0, 0, 0);
        }
        __builtin_amdgcn_s_setprio(0);
    }

    // store bf16 partial: rows n0+wid*16+4g+r, cols h*128 + di*16 + lo
#pragma unroll
    for (int di = 0; di < 8; ++di)
#pragma unroll
        for (int r = 0; r < 4; ++r)
            part[((size_t)kc * N_ATOMS + n0 + wid * 16 + 4 * g + r) * H_CH
                 + h * D_HEAD + di * 16 + lo] = f2bf(osg[di][r]);
}

// ---------------------------------------------------------------------------
// Kernel 3: LayerNorm of sum of 8 bf16 partials (biased var, eps 1e-7), bf16 out
// ---------------------------------------------------------------------------
__global__ __launch_bounds__(256) void layernorm8_k(const unsigned short* __restrict__ part,
                                                    const float* __restrict__ gm,
                                                    const float* __restrict__ bt,
                                                    unsigned short* __restrict__ y) {
    const int row = blockIdx.x;
    const int t = threadIdx.x;
    const size_t base = (size_t)row * H_CH;
    float4 v = make_float4(0.f, 0.f, 0.f, 0.f);
#pragma unroll
    for (int p = 0; p < 8; ++p) {
        const ushort4_t a = ((const ushort4_t*)(part + (size_t)p * N_ATOMS * H_CH + base))[t];
        v.x += bf2f(a[0]); v.y += bf2f(a[1]); v.z += bf2f(a[2]); v.w += bf2f(a[3]);
    }

    float s  = v.x + v.y + v.z + v.w;
    float s2 = v.x * v.x + v.y * v.y + v.z * v.z + v.w * v.w;
#pragma unroll
    for (int o = 1; o < 64; o <<= 1) {
        s  += __shfl_xor(s, o);
        s2 += __shfl_xor(s2, o);
    }
    __shared__ float red[8];
    const int wid = t >> 6;
    if ((t & 63) == 0) { red[wid] = s; red[wid + 4] = s2; }
    __syncthreads();
    const float ts  = red[0] + red[1] + red[2] + red[3];
    const float ts2 = red[4] + red[5] + red[6] + red[7];

    const float mean = ts * (1.0f / (float)H_CH);
    const float var  = ts2 * (1.0f / (float)H_CH) - mean * mean;
    const float rstd = rsqrtf(var + 1e-7f);

    const float4 gv = ((const float4*)gm)[t];
    const float4 bv = ((const float4*)bt)[t];
    ushort4_t o;
    o[0] = f2bf((v.x - mean) * rstd * gv.x + bv.x);
    o[1] = f2bf((v.y - mean) * rstd * gv.y + bv.y);
    o[2] = f2bf((v.z - mean) * rstd * gv.z + bv.z);
    o[3] = f2bf((v.w - mean) * rstd * gv.w + bv.w);
    ((ushort4_t*)(y + base))[t] = o;
}

// ---------------------------------------------------------------------------
// Kernel 4: final GEMM  out[1024,512] = ln_o(bf16) @ Wo(f32, cast inline)^T + bo
// ---------------------------------------------------------------------------
__global__ __launch_bounds__(256) void gemm_out_k(const unsigned short* __restrict__ A,
                                                  const float* __restrict__ B,
                                                  const float* __restrict__ bias,
                                                  float* __restrict__ C) {
    __shared__ unsigned short As[64 * 40];
    __shared__ unsigned short Bs[64 * 40];
    const int t = threadIdx.x;
    const int w = t >> 6, lane = t & 63, g = lane >> 4, lo = lane & 15;
    const int m0 = blockIdx.x * 64, n0 = blockIdx.y * 64;
    const int srow = t >> 2, sc8 = (t & 3) * 8;

    f32x4 acc[4];
#pragma unroll
    for (int nf = 0; nf < 4; ++nf) acc[nf] = (f32x4){0.f, 0.f, 0.f, 0.f};

    const unsigned short* gA = A + (size_t)(m0 + srow) * H_CH + sc8;
    const float* gB = B + (size_t)(n0 + srow) * H_CH + sc8;
    const int swr = srow * 40 + sc8;

    for (int k0 = 0; k0 < H_CH; k0 += 32) {
        const short8_t av = *(const short8_t*)(gA + k0);
        const float4 b0 = *(const float4*)(gB + k0);
        const float4 b1 = *(const float4*)(gB + k0 + 4);
        short8_t bvv;
        bvv[0]=f2bf(b0.x); bvv[1]=f2bf(b0.y); bvv[2]=f2bf(b0.z); bvv[3]=f2bf(b0.w);
        bvv[4]=f2bf(b1.x); bvv[5]=f2bf(b1.y); bvv[6]=f2bf(b1.z); bvv[7]=f2bf(b1.w);
        __syncthreads();
        *(short8_t*)&As[swr] = av;
        *(short8_t*)&Bs[swr] = bvv;
        __syncthreads();
        const short8_t af = *(const short8_t*)&As[(w * 16 + lo) * 40 + g * 8];
#pragma unroll
        for (int nf = 0; nf < 4; ++nf) {
            const short8_t bf = *(const short8_t*)&Bs[(nf * 16 + lo) * 40 + g * 8];
            acc[nf] = __builtin_amdgcn_mfma_f32_16x16x32_bf16(af, bf, acc[nf], 0, 0, 0);
        }
    }

#pragma unroll
    for (int nf = 0; nf < 4; ++nf) {
        const int col = n0 + nf * 16 + lo;
        const float bvv = bias[col];
#pragma unroll
        for (int r = 0; r < 4; ++r) {
            const int row = m0 + w * 16 + 4 * g + r;
            C[(size_t)row * IN_CH + col] = acc[nf][r] + bvv;
        }
    }
}

// ---------------------------------------------------------------------------
// Launch
// ---------------------------------------------------------------------------
extern "C" void kernel_launch(void* const* d_in, const int* in_sizes, int n_in,
                              void* d_out, int out_size, void* d_ws, size_t ws_size,
                              hipStream_t stream) {
    (void)in_sizes; (void)n_in; (void)out_size; (void)ws_size;
    const float* q         = (const float*)d_in[0];
    const float* k         = (const float*)d_in[1];
    const float* v         = (const float*)d_in[2];
    const float* envelope  = (const float*)d_in[3];
    const float* attn_bias = (const float*)d_in[4];
    const float* Wq        = (const float*)d_in[5];
    const float* bq        = (const float*)d_in[6];
    const float* Wk        = (const float*)d_in[7];
    const float* bk        = (const float*)d_in[8];
    const float* Wv        = (const float*)d_in[9];
    const float* bv        = (const float*)d_in[10];
    const float* ln_g      = (const float*)d_in[11];
    const float* ln_b      = (const float*)d_in[12];
    const float* Wo        = (const float*)d_in[13];
    const float* bo        = (const float*)d_in[14];
    const int* atom_index  = (const int*)d_in[15];
    const int* batch_index = (const int*)d_in[16];
    const int* edge_map    = (const int*)d_in[17];
    float* out = (float*)d_out;

    char* w8 = (char*)d_ws;
    unsigned short* SpT   = (unsigned short*)(w8);                      // 0..16M
    unsigned short* abT   = (unsigned short*)(w8 + (16u << 20));        // 16..32M
    unsigned short* partb = (unsigned short*)(w8 + (32u << 20));        // 32..48M
    unsigned short* vbuf  = (unsigned short*)(w8 + (48u << 20));        // 48..50M
    unsigned short* qb    = (unsigned short*)(w8 + (50u << 20));        // 50..52M
    unsigned short* kb    = (unsigned short*)(w8 + (52u << 20));        // 52..54M
    unsigned short* ln_o  = (unsigned short*)(w8 + (54u << 20));        // 54..56M
    unsigned short* rrbf  = (unsigned short*)(w8 + (56u << 20));        // 1 MB bf16 [H][64][1024]
    int2*           pkenv = (int2*)          (w8 + (58u << 20));        // 64 KB

    transpose_bias_pack_k<<<dim3(M_ENV / 64, N_ATOMS / 64), 256, 0, stream>>>(
        attn_bias, atom_index, edge_map, batch_index, envelope, abT, pkenv);

    Proj3 pj;
    pj.A[0] = q;   pj.A[1] = k;   pj.A[2] = v;
    pj.B[0] = Wq;  pj.B[1] = Wk;  pj.B[2] = Wv;
    pj.bia[0] = bq; pj.bia[1] = bk; pj.bia[2] = bv;
    pj.C[0] = qb;  pj.C[1] = kb;  pj.C[2] = vbuf;
    proj3_k<<<dim3(16, 16, 3), 256, 0, stream>>>(pj);

    spre_k<<<dim3(16, 16, H_HEADS), 256, 0, stream>>>(kb, qb, SpT);

    lsum5_k<<<dim3(8, H_HEADS, B_SEG), 256, 0, stream>>>(SpT, abT, pkenv,
                                                         batch_index, rrbf);

    pv7_k<<<dim3(N_ATOMS / 64, H_HEADS, 8), 256, 0, stream>>>(
        SpT, vbuf, abT, pkenv, rrbf, partb);

    layernorm8_k<<<N_ATOMS, 256, 0, stream>>>(partb, ln_g, ln_b, ln_o);

    gemm_out_k<<<dim3(16, 8), 256, 0, stream>>>(ln_o, Wo, bo, out);
}